// Round 6
// baseline (1048.786 us; speedup 1.0000x reference)
//
#include <hip/hip_runtime.h>
#include <hip/hip_bf16.h>

// Problem constants (B=32, D=256, H=W=64, K=6, CTX=256, TEMP=0.5)
#define NB 32
#define ND 256
#define NN_ 4096
#define NK 6

__device__ __forceinline__ float bf2f(unsigned int u) {
    union { unsigned int i; float f; } v; v.i = (u & 0xffffu) << 16; return v.f;
}
__device__ __forceinline__ unsigned short f2bf(float f) {
    __hip_bfloat16 h = __float2bfloat16(f);
    return *reinterpret_cast<unsigned short*>(&h);
}
__device__ __forceinline__ float gelu_exact(float x) {
    return 0.5f * x * (1.0f + erff(x * 0.70710678118654752f));
}

// Coalesced cooperative matvec chunk: 16 lanes per row; full row dot in all 16 lanes.
__device__ __forceinline__ float mv16(const float* __restrict__ W, int stride,
                                      int row, int l, const float* xs) {
    const float4* wr = reinterpret_cast<const float4*>(W + (size_t)row * stride + l * 16);
    const float4* xv = reinterpret_cast<const float4*>(xs + l * 16);
    float acc = 0.f;
#pragma unroll
    for (int i = 0; i < 4; ++i) {
        float4 w = wr[i], x = xv[i];
        acc += w.x * x.x + w.y * x.y + w.z * x.z + w.w * x.w;
    }
    acc += __shfl_xor(acc, 1, 64);
    acc += __shfl_xor(acc, 2, 64);
    acc += __shfl_xor(acc, 4, 64);
    acc += __shfl_xor(acc, 8, 64);
    return acc;
}

// ---------------- setup: init, sw1p pad, M = k_w^T @ q_w (tile GEMM), m0/u/c0,
// context MLP (192 blocks), qln0 ----------------
__global__ void k_setup(float* __restrict__ mask, float* __restrict__ accz,
                        float* __restrict__ state, float* __restrict__ stateT,
                        const float* __restrict__ sw1, float* __restrict__ sw1p,
                        const float* __restrict__ tc, const float* __restrict__ w1,
                        const float* __restrict__ b1, const float* __restrict__ w2,
                        const float* __restrict__ b2, float* __restrict__ clue,
                        const float* __restrict__ qn_g, const float* __restrict__ qn_b,
                        const float* __restrict__ k_w, const float* __restrict__ q_w,
                        const float* __restrict__ q_b, const float* __restrict__ k_b,
                        float* __restrict__ M, float* __restrict__ m0,
                        float* __restrict__ u, float* __restrict__ c0v,
                        float* __restrict__ qlnG) {
    int blk = blockIdx.x, t = threadIdx.x;
    if (blk < 128) {   // mask = 1
        reinterpret_cast<float4*>(mask)[blk * 256 + t] = make_float4(1.f, 1.f, 1.f, 1.f);
        return;
    }
    if (blk == 128) {  // accs(768) + cnt(192) + stopacc(32) + pad(32) = 1024 floats
        reinterpret_cast<float4*>(accz)[t] = make_float4(0.f, 0.f, 0.f, 0.f);
        return;
    }
    if (blk < 137) {   // state [32][256] = 0
        reinterpret_cast<float4*>(state)[(blk - 129) * 256 + t] = make_float4(0.f, 0.f, 0.f, 0.f);
        return;
    }
    if (blk < 145) {   // stateT [256][32] = 0
        reinterpret_cast<float4*>(stateT)[(blk - 137) * 256 + t] = make_float4(0.f, 0.f, 0.f, 0.f);
        return;
    }
    if (blk < 178) {   // sw1p [128][264] padded copy of sw1 [128][257]
        int f4 = (blk - 145) * 256 + t;
        int j = f4 * 4, row = j / 264, col = j - row * 264;
        float v[4];
#pragma unroll
        for (int e = 0; e < 4; ++e) {
            int cc = col + e;
            v[e] = (cc < 257) ? sw1[row * 257 + cc] : 0.f;
        }
        *reinterpret_cast<float4*>(sw1p + j) = make_float4(v[0], v[1], v[2], v[3]);
        return;
    }
    if (blk < 242) {   // M[i][j] = sum_d k_w[d][i] * q_w[d][j] ; 8x8 grid of 32x32 tiles
        __shared__ float aL[32][33], bL[32][33];
        int tt = blk - 178, I = (tt >> 3) * 32, J = (tt & 7) * 32;
        int rg = t >> 5, j = t & 31;
        float acc[4] = {0, 0, 0, 0};
        for (int dc = 0; dc < 8; ++dc) {
            __syncthreads();
            int dl = t >> 3, c4 = (t & 7) * 4;
            float4 av = *reinterpret_cast<const float4*>(k_w + (size_t)(dc * 32 + dl) * 256 + I + c4);
            float4 bv = *reinterpret_cast<const float4*>(q_w + (size_t)(dc * 32 + dl) * 256 + J + c4);
            aL[dl][c4] = av.x; aL[dl][c4 + 1] = av.y; aL[dl][c4 + 2] = av.z; aL[dl][c4 + 3] = av.w;
            bL[dl][c4] = bv.x; bL[dl][c4 + 1] = bv.y; bL[dl][c4 + 2] = bv.z; bL[dl][c4 + 3] = bv.w;
            __syncthreads();
#pragma unroll 8
            for (int dl2 = 0; dl2 < 32; ++dl2) {
                float bb = bL[dl2][j];
                acc[0] += aL[dl2][rg * 4 + 0] * bb;
                acc[1] += aL[dl2][rg * 4 + 1] * bb;
                acc[2] += aL[dl2][rg * 4 + 2] * bb;
                acc[3] += aL[dl2][rg * 4 + 3] * bb;
            }
        }
#pragma unroll
        for (int k2 = 0; k2 < 4; ++k2)
            M[(size_t)(I + rg * 4 + k2) * 256 + J + j] = acc[k2];
        return;
    }
    if (blk == 242) {  // m0 = k_w^T @ q_b ; u = q_w^T @ k_b ; c0 = q_b . k_b
        __shared__ float sredc[4];
        float a0 = 0.f, a1 = 0.f;
#pragma unroll 8
        for (int d = 0; d < 256; ++d) {
            a0 += k_w[(size_t)d * 256 + t] * q_b[d];
            a1 += q_w[(size_t)d * 256 + t] * k_b[d];
        }
        m0[t] = a0; u[t] = a1;
        float p = q_b[t] * k_b[t];
#pragma unroll
        for (int off = 32; off > 0; off >>= 1) p += __shfl_down(p, off, 64);
        if ((t & 63) == 0) sredc[t >> 6] = p;
        __syncthreads();
        if (t == 0) c0v[0] = sredc[0] + sredc[1] + sredc[2] + sredc[3];
        return;
    }
    // ---- context MLP: block = (b, ch) ----
    __shared__ __align__(16) float tcs[256];
    __shared__ __align__(16) float h1[256];
    __shared__ __align__(16) float c0sh[256];
    __shared__ float sred[8];
    int mb = blk - 243, b = mb / 6, ch = mb % 6;
    int lane = t & 63, wv = t >> 6, l = t & 15, rq = t >> 4;
    tcs[t] = tc[b * 256 + t];
    __syncthreads();
#pragma unroll 4
    for (int bi = 0; bi < 16; ++bi) {
        int row = bi * 16 + rq;
        float acc = mv16(w1, 256, row, l, tcs) + b1[row];
        if (l == 0) h1[row] = gelu_exact(acc);
    }
    __syncthreads();
#pragma unroll 4
    for (int bi = 0; bi < 16; ++bi) {
        int lrow = bi * 16 + rq, row = ch * 256 + lrow;
        float a2 = mv16(w2, 256, row, l, h1) + b2[row];
        float cv = fminf(fmaxf(a2, -10.f), 10.f);
        if (l == 0) {
            clue[b * 1536 + row] = cv;
            if (ch == 0) c0sh[lrow] = cv;
        }
    }
    if (ch != 0) return;
    __syncthreads();
    // qln0 = LN(clue0)
    float x0 = c0sh[t];
    float s = x0, s2 = x0 * x0;
#pragma unroll
    for (int off = 32; off > 0; off >>= 1) {
        s += __shfl_down(s, off, 64);
        s2 += __shfl_down(s2, off, 64);
    }
    if (lane == 0) { sred[wv] = s; sred[4 + wv] = s2; }
    __syncthreads();
    float mu = (sred[0] + sred[1] + sred[2] + sred[3]) * (1.f / 256.f);
    float var = (sred[4] + sred[5] + sred[6] + sred[7]) * (1.f / 256.f) - mu * mu;
    float rs = rsqrtf(var + 1e-5f);
    qlnG[t * 32 + b] = (x0 - mu) * rs * qn_g[t] + qn_b[t];
}

// ---------------- fused transpose + LN -> ft (bf16, row-major [b][n][256]) ----------
__global__ __launch_bounds__(256, 4) void k_ln(
    const float* __restrict__ features, const float* __restrict__ fn_g,
    const float* __restrict__ fn_b, unsigned short* __restrict__ ft) {
    int tile = blockIdx.x, b = blockIdx.y, t = threadIdx.x;
    int lane = t & 63, wv = t >> 6, l = t & 15;
    __shared__ __align__(16) unsigned short A[64 * 264];
    __shared__ __align__(16) float redS[4][16][8];
    unsigned int* A32 = reinterpret_cast<unsigned int*>(A);

    int n0 = tile * 64, dq = t >> 4;
    const float* fb = features + (size_t)b * 1048576 + (size_t)dq * 16 * 4096 + n0 + l * 4;
    unsigned int u[4][8];
    float s[4] = {0, 0, 0, 0}, s2[4] = {0, 0, 0, 0};
#pragma unroll
    for (int p = 0; p < 16; ++p) {
        float4 v = *reinterpret_cast<const float4*>(fb + (size_t)p * 4096);
        s[0] += v.x; s2[0] += v.x * v.x;
        s[1] += v.y; s2[1] += v.y * v.y;
        s[2] += v.z; s2[2] += v.z * v.z;
        s[3] += v.w; s2[3] += v.w * v.w;
        unsigned int b0 = f2bf(v.x), b1_ = f2bf(v.y), b2_ = f2bf(v.z), b3_ = f2bf(v.w);
        if ((p & 1) == 0) {
            u[0][p >> 1] = b0; u[1][p >> 1] = b1_; u[2][p >> 1] = b2_; u[3][p >> 1] = b3_;
        } else {
            u[0][p >> 1] |= b0 << 16; u[1][p >> 1] |= b1_ << 16;
            u[2][p >> 1] |= b2_ << 16; u[3][p >> 1] |= b3_ << 16;
        }
    }
#pragma unroll
    for (int k = 0; k < 4; ++k) {
        s[k]  += __shfl_xor(s[k], 16, 64);  s[k]  += __shfl_xor(s[k], 32, 64);
        s2[k] += __shfl_xor(s2[k], 16, 64); s2[k] += __shfl_xor(s2[k], 32, 64);
    }
    if (lane < 16) {
        *reinterpret_cast<float4*>(&redS[wv][lane][0]) = make_float4(s[0], s[1], s[2], s[3]);
        *reinterpret_cast<float4*>(&redS[wv][lane][4]) = make_float4(s2[0], s2[1], s2[2], s2[3]);
    }
    __syncthreads();
    float mm[4], rr[4];
#pragma unroll
    for (int k = 0; k < 4; ++k) {
        float ts_ = redS[0][l][k] + redS[1][l][k] + redS[2][l][k] + redS[3][l][k];
        float t2  = redS[0][l][4 + k] + redS[1][l][4 + k] + redS[2][l][4 + k] + redS[3][l][4 + k];
        float mean = ts_ * (1.f / 256.f);
        float var = t2 * (1.f / 256.f) - mean * mean;
        mm[k] = mean; rr[k] = rsqrtf(var + 1e-5f);
    }
    float gg[16], ee[16];
#pragma unroll
    for (int j4 = 0; j4 < 4; ++j4) {
        *reinterpret_cast<float4*>(&gg[j4 * 4]) =
            *reinterpret_cast<const float4*>(fn_g + dq * 16 + j4 * 4);
        *reinterpret_cast<float4*>(&ee[j4 * 4]) =
            *reinterpret_cast<const float4*>(fn_b + dq * 16 + j4 * 4);
    }
#pragma unroll
    for (int k = 0; k < 4; ++k) {
        int rowl = l * 4 + k;
        unsigned int w[8];
#pragma unroll
        for (int j = 0; j < 8; ++j) {
            float x0 = bf2f(u[k][j]), x1 = bf2f(u[k][j] >> 16);
            unsigned int lo = f2bf((x0 - mm[k]) * rr[k] * gg[2 * j] + ee[2 * j]);
            unsigned int hi = f2bf((x1 - mm[k]) * rr[k] * gg[2 * j + 1] + ee[2 * j + 1]);
            w[j] = lo | (hi << 16);
        }
        uint4* dst = reinterpret_cast<uint4*>(&A32[rowl * 132 + dq * 8]);
        dst[0] = make_uint4(w[0], w[1], w[2], w[3]);
        dst[1] = make_uint4(w[4], w[5], w[6], w[7]);
    }
    __syncthreads();
    int ch = t & 31, rw = t >> 5;
    unsigned short* dst = ft + ((size_t)b * 4096 + n0) * 256;
#pragma unroll
    for (int ps = 0; ps < 8; ++ps) {
        int row = ps * 8 + rw;
        uint4 vv = *reinterpret_cast<const uint4*>(&A[row * 264 + ch * 8]);
        *reinterpret_cast<uint4*>(dst + (size_t)row * 256 + ch * 8) = vv;
    }
}

// ---------------- B: scores + partials; last block per b finishes: abar, ent, stop=0 ----
__global__ __launch_bounds__(256, 4) void k_score(
    const float* __restrict__ qpr, const float* __restrict__ qct,
    const unsigned short* __restrict__ ft, float* __restrict__ mask,
    float* __restrict__ escore, float* __restrict__ accs,
    float* __restrict__ pbuf, float* __restrict__ out_amap,
    unsigned int* __restrict__ cnt, float* __restrict__ abarG,
    float* __restrict__ entG, float* __restrict__ stopacc, int kstep) {
    int c = blockIdx.x, b = blockIdx.y, t = threadIdx.x;
    int lane = t & 63, wv = t >> 6;
    __shared__ __align__(16) float qs[256];
    __shared__ float lmsk[128];
    __shared__ __align__(16) float part2[4][256];
    __shared__ float sred[16];
    __shared__ int lastf;
    if (kstep > 0) {
        if (t < 128) {
            int n = c * 128 + t;
            float inv = 1.f / accs[(kstep - 1) * 128 + b];
            float e = escore[(size_t)b * 4096 + n];
            float m = mask[(size_t)b * 4096 + n];
            float a = fmaxf(e * inv, 1e-8f);
            out_amap[((size_t)(b * 6 + kstep - 1)) * 4096 + n] = a;
            float nm = fmaxf(m * (1.f - 0.9f * a), 1e-6f);
            mask[(size_t)b * 4096 + n] = nm;
            lmsk[t] = logf(nm);
        }
    } else if (t < 128) lmsk[t] = 0.f;
    qs[t] = qpr[b * 256 + t];
    __syncthreads();
    int l = t & 15, rg = t >> 4;
    float qq[16];
#pragma unroll
    for (int i = 0; i < 16; ++i) qq[i] = qs[l * 16 + i];
    float qc = qct[b];
    float acc[16];
#pragma unroll
    for (int i = 0; i < 16; ++i) acc[i] = 0.f;
    float dsum = 0.f, erow = 0.f, ecol = 0.f, elg = 0.f;
    const unsigned short* fb = ft + ((size_t)b * 4096 + c * 128) * 256 + l * 16;
#pragma unroll 2
    for (int rr = 0; rr < 8; ++rr) {
        int nl = rr * 16 + rg;
        int n = c * 128 + nl;
        const uint4* p = reinterpret_cast<const uint4*>(fb + (size_t)nl * 256);
        uint4 r0 = p[0], r1 = p[1];
        float v[16];
        v[0]  = bf2f(r0.x); v[1]  = bf2f(r0.x >> 16);
        v[2]  = bf2f(r0.y); v[3]  = bf2f(r0.y >> 16);
        v[4]  = bf2f(r0.z); v[5]  = bf2f(r0.z >> 16);
        v[6]  = bf2f(r0.w); v[7]  = bf2f(r0.w >> 16);
        v[8]  = bf2f(r1.x); v[9]  = bf2f(r1.x >> 16);
        v[10] = bf2f(r1.y); v[11] = bf2f(r1.y >> 16);
        v[12] = bf2f(r1.z); v[13] = bf2f(r1.z >> 16);
        v[14] = bf2f(r1.w); v[15] = bf2f(r1.w >> 16);
        float dot = 0.f;
#pragma unroll
        for (int i = 0; i < 16; ++i) dot += v[i] * qq[i];
        dot += __shfl_xor(dot, 1, 64);
        dot += __shfl_xor(dot, 2, 64);
        dot += __shfl_xor(dot, 4, 64);
        dot += __shfl_xor(dot, 8, 64);
        float sc = (dot + qc) * 0.0625f + lmsk[nl];
        sc = fminf(fmaxf(sc, -50.f), 50.f);
        float lg = fminf(fmaxf(sc * 2.f, -50.f), 50.f);
        float e = expf(lg);
        if (l == 0) escore[(size_t)b * 4096 + n] = e;
        dsum += e; elg += e * lg;
        erow += e * (float)(n >> 6);
        ecol += e * (float)(n & 63);
#pragma unroll
        for (int i = 0; i < 16; ++i) acc[i] += e * v[i];
    }
#pragma unroll
    for (int i = 0; i < 16; ++i) {
        acc[i] += __shfl_xor(acc[i], 16, 64);
        acc[i] += __shfl_xor(acc[i], 32, 64);
    }
    if (lane < 16) {
#pragma unroll
        for (int i4 = 0; i4 < 4; ++i4)
            *reinterpret_cast<float4*>(&part2[wv][lane * 16 + i4 * 4]) =
                make_float4(acc[i4 * 4], acc[i4 * 4 + 1], acc[i4 * 4 + 2], acc[i4 * 4 + 3]);
    }
    dsum *= 0.0625f; erow *= 0.0625f; ecol *= 0.0625f; elg *= 0.0625f;
#pragma unroll
    for (int off = 32; off > 0; off >>= 1) {
        dsum += __shfl_down(dsum, off, 64);
        erow += __shfl_down(erow, off, 64);
        ecol += __shfl_down(ecol, off, 64);
        elg  += __shfl_down(elg, off, 64);
    }
    if (lane == 0) {
        sred[wv] = dsum; sred[4 + wv] = erow; sred[8 + wv] = ecol; sred[12 + wv] = elg;
    }
    __syncthreads();
    if (t == 0) {
        atomicAdd(&accs[kstep * 128 + b],      sred[0] + sred[1] + sred[2] + sred[3]);
        atomicAdd(&accs[kstep * 128 + 32 + b], sred[4] + sred[5] + sred[6] + sred[7]);
        atomicAdd(&accs[kstep * 128 + 64 + b], sred[8] + sred[9] + sred[10] + sred[11]);
        atomicAdd(&accs[kstep * 128 + 96 + b], sred[12] + sred[13] + sred[14] + sred[15]);
    }
    float sum = part2[0][t] + part2[1][t] + part2[2][t] + part2[3][t];
    pbuf[((size_t)c * 32 + b) * 256 + t] = sum;
    __threadfence();
    __syncthreads();
    if (t == 0) {
        unsigned int o = atomicAdd(&cnt[kstep * 32 + b], 1u);
        lastf = (o == 31u);
    }
    __syncthreads();
    if (lastf) {     // finisher: all 32 c-blocks for this (kstep,b) are done
        __threadfence();
        float S = accs[kstep * 128 + b];
        float inv = 1.f / S;
        float sm = 0.f;
#pragma unroll
        for (int c2 = 0; c2 < 32; ++c2) sm += pbuf[((size_t)c2 * 32 + b) * 256 + t];
        abarG[t * 32 + b] = sm * inv;
        if (t == 0) {
            float el = accs[kstep * 128 + 96 + b];
            entG[b] = -(el * inv - logf(S)) * 0.12022458674074826f;
            stopacc[b] = 0.f;
        }
    }
}

// ---------------- GEMM1: attended = v_w@abar + v_b (rows 0..255);
// gh = whh@h + bhh (rows 256..1023). Weights read once. ----------------
__global__ __launch_bounds__(256, 2) void k_gemm1(
    const float* __restrict__ v_w, const float* __restrict__ v_b,
    const float* __restrict__ whh, const float* __restrict__ bhh,
    const float* __restrict__ abarG, const float* __restrict__ stateT,
    float* __restrict__ attG, float* __restrict__ ghG) {
    __shared__ float xL[8192];
    __shared__ float wL[8192];
    int blk = blockIdx.x, t = threadIdx.x;
    const float* X; const float* Wg; const float* bias; float* out; int r0;
    if (blk < 8) { r0 = blk * 32; Wg = v_w + (size_t)r0 * 256; bias = v_b + r0;
                   X = abarG; out = attG + r0 * 32; }
    else { r0 = (blk - 8) * 32; Wg = whh + (size_t)r0 * 256; bias = bhh + r0;
           X = stateT; out = ghG + r0 * 32; }
    float4* xL4 = reinterpret_cast<float4*>(xL);
    float4* wL4 = reinterpret_cast<float4*>(wL);
    const float4* Xg4 = reinterpret_cast<const float4*>(X);
    const float4* Wg4 = reinterpret_cast<const float4*>(Wg);
#pragma unroll
    for (int j = 0; j < 8; ++j) {
        xL4[j * 256 + t] = Xg4[j * 256 + t];
        wL4[j * 256 + t] = Wg4[j * 256 + t];
    }
    __syncthreads();
    int rg = t >> 5, b = t & 31;
    float acc[4] = {0, 0, 0, 0};
#pragma unroll 8
    for (int d = 0; d < 256; ++d) {
        float xv = xL[d * 32 + b];
        acc[0] += wL[(rg * 4 + 0) * 256 + d] * xv;
        acc[1] += wL[(rg * 4 + 1) * 256 + d] * xv;
        acc[2] += wL[(rg * 4 + 2) * 256 + d] * xv;
        acc[3] += wL[(rg * 4 + 3) * 256 + d] * xv;
    }
#pragma unroll
    for (int k2 = 0; k2 < 4; ++k2)
        out[(rg * 4 + k2) * 32 + b] = acc[k2] + bias[rg * 4 + k2];
}

// ---------------- GEMM2: gi = wih@attended + bih (24 blk); stop rows of sw1p (4 blk) ----
__global__ __launch_bounds__(256, 2) void k_gemm2(
    const float* __restrict__ wih, const float* __restrict__ bih,
    const float* __restrict__ sw1p, const float* __restrict__ sb1,
    const float* __restrict__ sw2, const float* __restrict__ entG,
    const float* __restrict__ attG, float* __restrict__ giG,
    float* __restrict__ stopacc) {
    __shared__ float xL[8192];
    __shared__ float wL[8192];
    __shared__ float w256[32];
    __shared__ float pB[8][32];
    int blk = blockIdx.x, t = threadIdx.x;
    float4* xL4 = reinterpret_cast<float4*>(xL);
    float4* wL4 = reinterpret_cast<float4*>(wL);
    const float4* Xg4 = reinterpret_cast<const float4*>(attG);
#pragma unroll
    for (int j = 0; j < 8; ++j) xL4[j * 256 + t] = Xg4[j * 256 + t];
    int rg = t >> 5, b = t & 31;
    if (blk < 24) {
        int r0 = blk * 32;
        const float4* Wg4 = reinterpret_cast<const float4*>(wih + (size_t)r0 * 256);
#pragma unroll
        for (int j = 0; j < 8; ++j) wL4[j * 256 + t] = Wg4[j * 256 + t];
        __syncthreads();
        float acc[4] = {0, 0, 0, 0};
#pragma unroll 8
        for (int d = 0; d < 256; ++d) {
            float xv = xL[d * 32 + b];
            acc[0] += wL[(rg * 4 + 0) * 256 + d] * xv;
            acc[1] += wL[(rg * 4 + 1) * 256 + d] * xv;
            acc[2] += wL[(rg * 4 + 2) * 256 + d] * xv;
            acc[3] += wL[(rg * 4 + 3) * 256 + d] * xv;
        }
#pragma unroll
        for (int k2 = 0; k2 < 4; ++k2)
            giG[(size_t)(r0 + rg * 4 + k2) * 32 + b] = acc[k2] + bih[r0 + rg * 4 + k2];
    } else {
        int sr0 = (blk - 24) * 32;
#pragma unroll
        for (int j = 0; j < 8; ++j) {
            int f4 = j * 256 + t;
            int row = f4 >> 6, c4 = f4 & 63;
            wL4[f4] = *reinterpret_cast<const float4*>(sw1p + (size_t)(sr0 + row) * 264 + c4 * 4);
        }
        if (t < 32) w256[t] = sw1p[(size_t)(sr0 + t) * 264 + 256];
        __syncthreads();
        float acc[4] = {0, 0, 0, 0};
#pragma unroll 8
        for (int d = 0; d < 256; ++d) {
            float xv = xL[d * 32 + b];
            acc[0] += wL[(rg * 4 + 0) * 256 + d] * xv;
            acc[1] += wL[(rg * 4 + 1) * 256 + d] * xv;
            acc[2] += wL[(rg * 4 + 2) * 256 + d] * xv;
            acc[3] += wL[(rg * 4 + 3) * 256 + d] * xv;
        }
        float ent = entG[b], gsum = 0.f;
#pragma unroll
        for (int k2 = 0; k2 < 4; ++k2) {
            int sr = sr0 + rg * 4 + k2;
            float av = acc[k2] + sb1[sr] + ent * w256[rg * 4 + k2];
            gsum += gelu_exact(av) * sw2[sr];
        }
        pB[rg][b] = gsum;
        __syncthreads();
        if (t < 32) {
            float sv = pB[0][t] + pB[1][t] + pB[2][t] + pB[3][t]
                     + pB[4][t] + pB[5][t] + pB[6][t] + pB[7][t];
            atomicAdd(&stopacc[t], sv);
        }
    }
}

// ---------------- FIN: per-b: stop/centroid out; GRU combine -> h; LN -> qln.
// blocks 32..63 (k==5 only): amap(5). ----------------
__global__ void k_fin(
    const float* __restrict__ accs, const float* __restrict__ giG,
    const float* __restrict__ ghG, float* __restrict__ state,
    float* __restrict__ stateT, const float* __restrict__ clue,
    const float* __restrict__ qn_g, const float* __restrict__ qn_b,
    const float* __restrict__ stopacc, const float* __restrict__ sb2,
    const float* __restrict__ escore, float* __restrict__ out_amap,
    float* __restrict__ qlnG, float* __restrict__ out_cent,
    float* __restrict__ out_stop, int kstep) {
    int bb = blockIdx.x, t = threadIdx.x;
    if (bb >= 32) {    // amap(5)
        int b = bb - 32;
        float inv = 1.f / accs[5 * 128 + b];
#pragma unroll
        for (int j = 0; j < 4; ++j) {
            int n4 = (j * 256 + t) * 4;
            float4 e4 = *reinterpret_cast<const float4*>(&escore[(size_t)b * 4096 + n4]);
            *reinterpret_cast<float4*>(&out_amap[((size_t)(b * 6 + 5)) * 4096 + n4]) =
                make_float4(fmaxf(e4.x * inv, 1e-8f), fmaxf(e4.y * inv, 1e-8f),
                            fmaxf(e4.z * inv, 1e-8f), fmaxf(e4.w * inv, 1e-8f));
        }
        return;
    }
    int b = bb, lane = t & 63, wv = t >> 6;
    __shared__ float sred[8];
    float S = accs[kstep * 128 + b];
    float inv = 1.f / S;
    if (t == 0) {
        out_stop[b * 6 + kstep] = 4.f * tanhf((sb2[0] + stopacc[b]) * 0.25f);
        out_cent[(b * 6 + kstep) * 2 + 0] = accs[kstep * 128 + 32 + b] * inv;
        out_cent[(b * 6 + kstep) * 2 + 1] = accs[kstep * 128 + 64 + b] * inv;
    }
    if (kstep == 5) return;
    float hprev = state[b * 256 + t];
    float gi_r = giG[(size_t)t * 32 + b],         gh_r = ghG[(size_t)t * 32 + b];
    float gi_z = giG[(size_t)(256 + t) * 32 + b], gh_z = ghG[(size_t)(256 + t) * 32 + b];
    float gi_n = giG[(size_t)(512 + t) * 32 + b], gh_n = ghG[(size_t)(512 + t) * 32 + b];
    float r = 1.f / (1.f + expf(-(gi_r + gh_r)));
    float z = 1.f / (1.f + expf(-(gi_z + gh_z)));
    float nn = tanhf(gi_n + r * gh_n);
    float h = (1.f - z) * nn + z * hprev;
    state[b * 256 + t] = h;
    stateT[t * 32 + b] = h;
    float x = clue[((size_t)b * 6 + kstep + 1) * 256 + t] + h;
    float s = x, s2v = x * x;
#pragma unroll
    for (int off = 32; off > 0; off >>= 1) {
        s += __shfl_down(s, off, 64);
        s2v += __shfl_down(s2v, off, 64);
    }
    if (lane == 0) { sred[wv] = s; sred[4 + wv] = s2v; }
    __syncthreads();
    float mu = (sred[0] + sred[1] + sred[2] + sred[3]) * (1.f / 256.f);
    float var = (sred[4] + sred[5] + sred[6] + sred[7]) * (1.f / 256.f) - mu * mu;
    float rs = rsqrtf(var + 1e-5f);
    qlnG[t * 32 + b] = (x - mu) * rs * qn_g[t] + qn_b[t];
}

// ---------------- GEMM3: qpr[b][.] = M@qln + m0 ; blk0 also qct = u.qln + c0 ----------
__global__ __launch_bounds__(256, 2) void k_gemm3(
    const float* __restrict__ M, const float* __restrict__ m0,
    const float* __restrict__ u, const float* __restrict__ c0v,
    const float* __restrict__ qlnG, float* __restrict__ qpr,
    float* __restrict__ qct) {
    __shared__ float xL[8192];
    __shared__ float wL[8192];
    __shared__ float pB[8][32];
    int blk = blockIdx.x, t = threadIdx.x;
    int r0 = blk * 32;
    float4* xL4 = reinterpret_cast<float4*>(xL);
    float4* wL4 = reinterpret_cast<float4*>(wL);
    const float4* Xg4 = reinterpret_cast<const float4*>(qlnG);
    const float4* Wg4 = reinterpret_cast<const float4*>(M + (size_t)r0 * 256);
#pragma unroll
    for (int j = 0; j < 8; ++j) {
        xL4[j * 256 + t] = Xg4[j * 256 + t];
        wL4[j * 256 + t] = Wg4[j * 256 + t];
    }
    __syncthreads();
    int rg = t >> 5, b = t & 31;
    float acc[4] = {0, 0, 0, 0};
#pragma unroll 8
    for (int d = 0; d < 256; ++d) {
        float xv = xL[d * 32 + b];
        acc[0] += wL[(rg * 4 + 0) * 256 + d] * xv;
        acc[1] += wL[(rg * 4 + 1) * 256 + d] * xv;
        acc[2] += wL[(rg * 4 + 2) * 256 + d] * xv;
        acc[3] += wL[(rg * 4 + 3) * 256 + d] * xv;
    }
#pragma unroll
    for (int k2 = 0; k2 < 4; ++k2) {
        int row = r0 + rg * 4 + k2;
        qpr[(size_t)b * 256 + row] = acc[k2] + m0[row];
    }
    if (blk == 0) {
        float sv = 0.f;
#pragma unroll 8
        for (int dd = 0; dd < 32; ++dd) {
            int d = rg * 32 + dd;
            sv += u[d] * xL[d * 32 + b];
        }
        pB[rg][b] = sv;
        __syncthreads();
        if (t < 32)
            qct[t] = pB[0][t] + pB[1][t] + pB[2][t] + pB[3][t]
                   + pB[4][t] + pB[5][t] + pB[6][t] + pB[7][t] + c0v[0];
    }
}

extern "C" void kernel_launch(void* const* d_in, const int* in_sizes, int n_in,
                              void* d_out, int out_size, void* d_ws, size_t ws_size,
                              hipStream_t stream) {
    const float* features     = (const float*)d_in[0];
    const float* task_context = (const float*)d_in[1];
    const float* ctx_w1 = (const float*)d_in[2];
    const float* ctx_b1 = (const float*)d_in[3];
    const float* ctx_w2 = (const float*)d_in[4];
    const float* ctx_b2 = (const float*)d_in[5];
    const float* q_w = (const float*)d_in[6];
    const float* q_b = (const float*)d_in[7];
    const float* k_w = (const float*)d_in[8];
    const float* k_b = (const float*)d_in[9];
    const float* v_w = (const float*)d_in[10];
    const float* v_b = (const float*)d_in[11];
    const float* qn_g = (const float*)d_in[12];
    const float* qn_b = (const float*)d_in[13];
    const float* fn_g = (const float*)d_in[14];
    const float* fn_b = (const float*)d_in[15];
    const float* stop_w1 = (const float*)d_in[16];
    const float* stop_b1 = (const float*)d_in[17];
    const float* stop_w2 = (const float*)d_in[18];
    const float* stop_b2 = (const float*)d_in[19];
    const float* gru_wih = (const float*)d_in[20];
    const float* gru_bih = (const float*)d_in[21];
    const float* gru_whh = (const float*)d_in[22];
    const float* gru_bhh = (const float*)d_in[23];

    // workspace layout (~67 MB)
    unsigned short* ft = (unsigned short*)d_ws;          // [32][4096][256] bf16
    float* sw1p  = (float*)(ft + (size_t)NB * NN_ * ND); // [128][264]
    float* clue  = sw1p + 128 * 264;                     // [32][6][256]
    float* state = clue + NB * NK * ND;                  // [32][256]
    float* stateT= state + NB * ND;                      // [256][32]
    float* qpr   = stateT + ND * NB;                     // [32][256]
    float* mask  = qpr + NB * ND;                        // [32][4096]
    float* escore= mask + NB * NN_;                      // [32][4096]
    float* accz  = escore + NB * NN_;                    // accs768 | cnt192 | stop32 | pad32
    float* accs  = accz;
    unsigned int* cnt = (unsigned int*)(accz + 768);
    float* stopacc = accz + 960;
    float* pbuf  = accz + 1024;                          // [32 c][32 b][256]
    float* M     = pbuf + 32 * NB * ND;                  // [256][256]
    float* m0    = M + 65536;                            // [256]
    float* u     = m0 + 256;                             // [256]
    float* c0v   = u + 256;                              // [16]
    float* abarG = c0v + 16;                             // [256][32]
    float* attG  = abarG + ND * NB;                      // [256][32]
    float* ghG   = attG + ND * NB;                       // [768][32]
    float* giG   = ghG + 768 * NB;                       // [768][32]
    float* qlnG  = giG + 768 * NB;                       // [256][32]
    float* qctG  = qlnG + ND * NB;                       // [32]
    float* entG  = qctG + NB;                            // [32]

    float* out_cent = (float*)d_out;          // (B,K,2)
    float* out_amap = out_cent + NB * NK * 2; // (B,K,H,W)
    float* out_stop = out_amap + (size_t)NB * NK * NN_; // (B,K)

    k_setup<<<435, 256, 0, stream>>>(mask, accz, state, stateT, stop_w1, sw1p,
                                     task_context, ctx_w1, ctx_b1, ctx_w2, ctx_b2, clue,
                                     qn_g, qn_b, k_w, q_w, q_b, k_b, M, m0, u, c0v, qlnG);
    k_ln<<<dim3(64, 32), 256, 0, stream>>>(features, fn_g, fn_b, ft);
    k_gemm3<<<8, 256, 0, stream>>>(M, m0, u, c0v, qlnG, qpr, qctG);
    for (int k = 0; k < NK; ++k) {
        k_score<<<dim3(32, 32), 256, 0, stream>>>(qpr, qctG, ft, mask, escore, accs,
                                                  pbuf, out_amap, cnt, abarG, entG,
                                                  stopacc, k);
        k_gemm1<<<32, 256, 0, stream>>>(v_w, v_b, gru_whh, gru_bhh, abarG, stateT,
                                        attG, ghG);
        k_gemm2<<<28, 256, 0, stream>>>(gru_wih, gru_bih, sw1p, stop_b1, stop_w2,
                                        entG, attG, giG, stopacc);
        k_fin<<<(k == 5 ? 64 : 32), 256, 0, stream>>>(accs, giG, ghG, state, stateT,
                                        clue, qn_g, qn_b, stopacc, stop_b2,
                                        escore, out_amap, qlnG, out_cent, out_stop, k);
        if (k < 5)
            k_gemm3<<<8, 256, 0, stream>>>(M, m0, u, c0v, qlnG, qpr, qctG);
    }
}

// Round 7
// 841.501 us; speedup vs baseline: 1.2463x; 1.2463x over previous
//
#include <hip/hip_runtime.h>
#include <hip/hip_bf16.h>

// Problem constants (B=32, D=256, H=W=64, K=6, CTX=256, TEMP=0.5)
#define NB 32
#define ND 256
#define NN_ 4096
#define NK 6

__device__ __forceinline__ float bf2f(unsigned int u) {
    union { unsigned int i; float f; } v; v.i = (u & 0xffffu) << 16; return v.f;
}
__device__ __forceinline__ unsigned short f2bf(float f) {
    __hip_bfloat16 h = __float2bfloat16(f);
    return *reinterpret_cast<unsigned short*>(&h);
}
__device__ __forceinline__ float gelu_exact(float x) {
    return 0.5f * x * (1.0f + erff(x * 0.70710678118654752f));
}

// Coalesced cooperative matvec chunk: 16 lanes per row; full row dot in all 16 lanes.
__device__ __forceinline__ float mv16(const float* __restrict__ W, int stride,
                                      int row, int l, const float* xs) {
    const float4* wr = reinterpret_cast<const float4*>(W + (size_t)row * stride + l * 16);
    const float4* xv = reinterpret_cast<const float4*>(xs + l * 16);
    float acc = 0.f;
#pragma unroll
    for (int i = 0; i < 4; ++i) {
        float4 w = wr[i], x = xv[i];
        acc += w.x * x.x + w.y * x.y + w.z * x.z + w.w * x.w;
    }
    acc += __shfl_xor(acc, 1, 64);
    acc += __shfl_xor(acc, 2, 64);
    acc += __shfl_xor(acc, 4, 64);
    acc += __shfl_xor(acc, 8, 64);
    return acc;
}

// ---------------- setup: init, M = k_w^T@q_w, Wiv = wih@v_w, Wsv = sw1@v_w,
// biv/bsv/wsv256, m0/u/c0, context MLP -> clueT + qln0 ----------------
__global__ void k_setup(float* __restrict__ mask, float* __restrict__ accz,
                        float* __restrict__ sumevs, float* __restrict__ stateTs,
                        float* __restrict__ M, float* __restrict__ m0,
                        float* __restrict__ u, float* __restrict__ c0v,
                        float* __restrict__ Wiv, float* __restrict__ biv,
                        float* __restrict__ Wsv, float* __restrict__ bsv,
                        float* __restrict__ wsv256,
                        float* __restrict__ clueT, float* __restrict__ qlnG,
                        const float* __restrict__ k_w, const float* __restrict__ q_w,
                        const float* __restrict__ q_b, const float* __restrict__ k_b,
                        const float* __restrict__ wih, const float* __restrict__ bih,
                        const float* __restrict__ v_b,
                        const float* __restrict__ sw1, const float* __restrict__ sb1,
                        const float* __restrict__ tc, const float* __restrict__ w1,
                        const float* __restrict__ b1, const float* __restrict__ w2,
                        const float* __restrict__ b2,
                        const float* __restrict__ qn_g, const float* __restrict__ qn_b) {
    int blk = blockIdx.x, t = threadIdx.x;
    if (blk < 128) {   // mask = 1
        reinterpret_cast<float4*>(mask)[blk * 256 + t] = make_float4(1.f, 1.f, 1.f, 1.f);
        return;
    }
    if (blk == 128) {  // accz: accs 768 | stopp 128 | pad = 1024 floats
        reinterpret_cast<float4*>(accz)[t] = make_float4(0.f, 0.f, 0.f, 0.f);
        return;
    }
    if (blk < 145) {   // sumev0+sumev1 = 16384 floats
        reinterpret_cast<float4*>(sumevs)[(blk - 129) * 256 + t] = make_float4(0.f, 0.f, 0.f, 0.f);
        return;
    }
    if (blk < 161) {   // stateT0+stateT1 = 16384 floats
        reinterpret_cast<float4*>(stateTs)[(blk - 145) * 256 + t] = make_float4(0.f, 0.f, 0.f, 0.f);
        return;
    }
    if (blk < 225) {   // M[i][j] = sum_d k_w[d][i]*q_w[d][j]: 8x8 tiles of 32x32
        __shared__ float aL[32][33], bL[32][33];
        int tt = blk - 161, I = (tt >> 3) * 32, J = (tt & 7) * 32;
        int rg = t >> 5, j = t & 31;
        float acc[4] = {0, 0, 0, 0};
        for (int dc = 0; dc < 8; ++dc) {
            __syncthreads();
            int dl = t >> 3, c4 = (t & 7) * 4;
            float4 av = *reinterpret_cast<const float4*>(k_w + (size_t)(dc * 32 + dl) * 256 + I + c4);
            float4 bv = *reinterpret_cast<const float4*>(q_w + (size_t)(dc * 32 + dl) * 256 + J + c4);
            aL[dl][c4] = av.x; aL[dl][c4 + 1] = av.y; aL[dl][c4 + 2] = av.z; aL[dl][c4 + 3] = av.w;
            bL[dl][c4] = bv.x; bL[dl][c4 + 1] = bv.y; bL[dl][c4 + 2] = bv.z; bL[dl][c4 + 3] = bv.w;
            __syncthreads();
#pragma unroll 8
            for (int dl2 = 0; dl2 < 32; ++dl2) {
                float bb = bL[dl2][j];
                acc[0] += aL[dl2][rg * 4 + 0] * bb;
                acc[1] += aL[dl2][rg * 4 + 1] * bb;
                acc[2] += aL[dl2][rg * 4 + 2] * bb;
                acc[3] += aL[dl2][rg * 4 + 3] * bb;
            }
        }
#pragma unroll
        for (int k2 = 0; k2 < 4; ++k2)
            M[(size_t)(I + rg * 4 + k2) * 256 + J + j] = acc[k2];
        return;
    }
    if (blk < 417) {   // Wiv = wih @ v_w: 24x8 tiles
        __shared__ float aL[32][33], bL[32][33];
        int tt = blk - 225, I = (tt >> 3) * 32, J = (tt & 7) * 32;
        int rg = t >> 5, j = t & 31;
        float acc[4] = {0, 0, 0, 0};
        const float* v_w_g = q_w + 0;   // placeholder silence; real v_w passed via Wsv path? no:
        (void)v_w_g;
        for (int dc = 0; dc < 8; ++dc) {
            __syncthreads();
            int i = t >> 3, d4 = (t & 7) * 4;
            float4 av = *reinterpret_cast<const float4*>(wih + (size_t)(I + i) * 256 + dc * 32 + d4);
            aL[i][d4] = av.x; aL[i][d4 + 1] = av.y; aL[i][d4 + 2] = av.z; aL[i][d4 + 3] = av.w;
            // B = v_w rows (passed through u? no) -- v_w arrives via 'w2'? no. Use global v_w:
            float4 bv = *reinterpret_cast<const float4*>(b2 + 0);   // overwritten below
            (void)bv;
            __syncthreads();
            __syncthreads();
            (void)acc;
            break;
        }
        // NOTE: replaced below by k_setup2-free version -- see k_setupW.
        return;
    }
    // ---- context MLP: block = (b, ch) ----
    __shared__ __align__(16) float tcs[256];
    __shared__ __align__(16) float h1[256];
    __shared__ __align__(16) float c0sh[256];
    __shared__ float sred[8];
    int mb = blk - 417, b = mb / 6, ch = mb % 6;
    int lane = t & 63, wv = t >> 6, l = t & 15, rq = t >> 4;
    tcs[t] = tc[b * 256 + t];
    __syncthreads();
#pragma unroll 4
    for (int bi = 0; bi < 16; ++bi) {
        int row = bi * 16 + rq;
        float acc = mv16(w1, 256, row, l, tcs) + b1[row];
        if (l == 0) h1[row] = gelu_exact(acc);
    }
    __syncthreads();
#pragma unroll 4
    for (int bi = 0; bi < 16; ++bi) {
        int lrow = bi * 16 + rq, row = ch * 256 + lrow;
        float a2 = mv16(w2, 256, row, l, h1) + b2[row];
        float cv = fminf(fmaxf(a2, -10.f), 10.f);
        if (l == 0) {
            clueT[(size_t)(ch * 256 + lrow) * 32 + b] = cv;
            if (ch == 0) c0sh[lrow] = cv;
        }
    }
    if (ch != 0) return;
    __syncthreads();
    float x0 = c0sh[t];
    float s = x0, s2 = x0 * x0;
#pragma unroll
    for (int off = 32; off > 0; off >>= 1) {
        s += __shfl_down(s, off, 64);
        s2 += __shfl_down(s2, off, 64);
    }
    if (lane == 0) { sred[wv] = s; sred[4 + wv] = s2; }
    __syncthreads();
    float mu = (sred[0] + sred[1] + sred[2] + sred[3]) * (1.f / 256.f);
    float var = (sred[4] + sred[5] + sred[6] + sred[7]) * (1.f / 256.f) - mu * mu;
    float rs = rsqrtf(var + 1e-5f);
    qlnG[t * 32 + b] = (x0 - mu) * rs * qn_g[t] + qn_b[t];
}

// ---------------- setupW: weight-product GEMMs needing v_w ----------------
__global__ void k_setupW(const float* __restrict__ wih, const float* __restrict__ bih,
                         const float* __restrict__ v_w, const float* __restrict__ v_b,
                         const float* __restrict__ sw1, const float* __restrict__ sb1,
                         const float* __restrict__ k_w, const float* __restrict__ q_w,
                         const float* __restrict__ q_b, const float* __restrict__ k_b,
                         float* __restrict__ Wiv, float* __restrict__ biv,
                         float* __restrict__ Wsv, float* __restrict__ bsv,
                         float* __restrict__ wsv256,
                         float* __restrict__ m0, float* __restrict__ u,
                         float* __restrict__ c0v) {
    int blk = blockIdx.x, t = threadIdx.x;
    if (blk < 192) {   // Wiv = wih @ v_w: 24 row-tiles x 8 col-tiles
        __shared__ float aL[32][33], bL[32][33];
        int I = (blk >> 3) * 32, J = (blk & 7) * 32;
        int rg = t >> 5, j = t & 31;
        float acc[4] = {0, 0, 0, 0};
        for (int dc = 0; dc < 8; ++dc) {
            __syncthreads();
            int i = t >> 3, d4 = (t & 7) * 4;
            float4 av = *reinterpret_cast<const float4*>(wih + (size_t)(I + i) * 256 + dc * 32 + d4);
            aL[i][d4] = av.x; aL[i][d4 + 1] = av.y; aL[i][d4 + 2] = av.z; aL[i][d4 + 3] = av.w;
            float4 bv = *reinterpret_cast<const float4*>(v_w + (size_t)(dc * 32 + i) * 256 + J + d4);
            bL[i][d4] = bv.x; bL[i][d4 + 1] = bv.y; bL[i][d4 + 2] = bv.z; bL[i][d4 + 3] = bv.w;
            __syncthreads();
#pragma unroll 8
            for (int dl2 = 0; dl2 < 32; ++dl2) {
                float bb = bL[dl2][j];
                acc[0] += aL[rg * 4 + 0][dl2] * bb;
                acc[1] += aL[rg * 4 + 1][dl2] * bb;
                acc[2] += aL[rg * 4 + 2][dl2] * bb;
                acc[3] += aL[rg * 4 + 3][dl2] * bb;
            }
        }
#pragma unroll
        for (int k2 = 0; k2 < 4; ++k2)
            Wiv[(size_t)(I + rg * 4 + k2) * 256 + J + j] = acc[k2];
        return;
    }
    if (blk < 224) {   // Wsv = sw1[:, :256] @ v_w: 4x8 tiles (sw1 stride 257, scalar loads)
        __shared__ float aL[32][33], bL[32][33];
        int tt = blk - 192, I = (tt >> 3) * 32, J = (tt & 7) * 32;
        int rg = t >> 5, j = t & 31;
        float acc[4] = {0, 0, 0, 0};
        for (int dc = 0; dc < 8; ++dc) {
            __syncthreads();
            int i = t >> 3, d4 = (t & 7) * 4;
            aL[i][d4 + 0] = sw1[(size_t)(I + i) * 257 + dc * 32 + d4 + 0];
            aL[i][d4 + 1] = sw1[(size_t)(I + i) * 257 + dc * 32 + d4 + 1];
            aL[i][d4 + 2] = sw1[(size_t)(I + i) * 257 + dc * 32 + d4 + 2];
            aL[i][d4 + 3] = sw1[(size_t)(I + i) * 257 + dc * 32 + d4 + 3];
            float4 bv = *reinterpret_cast<const float4*>(v_w + (size_t)(dc * 32 + i) * 256 + J + d4);
            bL[i][d4] = bv.x; bL[i][d4 + 1] = bv.y; bL[i][d4 + 2] = bv.z; bL[i][d4 + 3] = bv.w;
            __syncthreads();
#pragma unroll 8
            for (int dl2 = 0; dl2 < 32; ++dl2) {
                float bb = bL[dl2][j];
                acc[0] += aL[rg * 4 + 0][dl2] * bb;
                acc[1] += aL[rg * 4 + 1][dl2] * bb;
                acc[2] += aL[rg * 4 + 2][dl2] * bb;
                acc[3] += aL[rg * 4 + 3][dl2] * bb;
            }
        }
#pragma unroll
        for (int k2 = 0; k2 < 4; ++k2)
            Wsv[(size_t)(I + rg * 4 + k2) * 256 + J + j] = acc[k2];
        return;
    }
    if (blk < 227) {   // biv = wih @ v_b + bih (3 x 256 rows)
        __shared__ __align__(16) float vbs[256];
        int bb = blk - 224;
        vbs[t] = v_b[t];
        __syncthreads();
        int l = t & 15, rq = t >> 4;
#pragma unroll 4
        for (int bi = 0; bi < 16; ++bi) {
            int row = bb * 256 + bi * 16 + rq;
            float val = mv16(wih, 256, row, l, vbs) + bih[row];
            if (l == 0) biv[row] = val;
        }
        return;
    }
    if (blk == 227) {  // bsv = sw1[:, :256]@v_b + sb1 ; wsv256 = sw1[:,256]
        __shared__ __align__(16) float vbs[256];
        vbs[t] = v_b[t];
        __syncthreads();
        if (t < 128) {
            float a = sb1[t];
#pragma unroll 8
            for (int e = 0; e < 256; ++e) a += sw1[(size_t)t * 257 + e] * vbs[e];
            bsv[t] = a;
            wsv256[t] = sw1[(size_t)t * 257 + 256];
        }
        return;
    }
    // blk == 228: m0 = k_w^T@q_b ; u = q_w^T@k_b ; c0 = q_b.k_b
    __shared__ float sredc[4];
    float a0 = 0.f, a1 = 0.f;
#pragma unroll 8
    for (int d = 0; d < 256; ++d) {
        a0 += k_w[(size_t)d * 256 + t] * q_b[d];
        a1 += q_w[(size_t)d * 256 + t] * k_b[d];
    }
    m0[t] = a0; u[t] = a1;
    float p = q_b[t] * k_b[t];
#pragma unroll
    for (int off = 32; off > 0; off >>= 1) p += __shfl_down(p, off, 64);
    if ((t & 63) == 0) sredc[t >> 6] = p;
    __syncthreads();
    if (t == 0) c0v[0] = sredc[0] + sredc[1] + sredc[2] + sredc[3];
}

// ---------------- fused transpose + LN -> ft (bf16, row-major [b][n][256]) ----------
__global__ __launch_bounds__(256, 4) void k_ln(
    const float* __restrict__ features, const float* __restrict__ fn_g,
    const float* __restrict__ fn_b, unsigned short* __restrict__ ft) {
    int tile = blockIdx.x, b = blockIdx.y, t = threadIdx.x;
    int lane = t & 63, wv = t >> 6, l = t & 15;
    __shared__ __align__(16) unsigned short A[64 * 264];
    __shared__ __align__(16) float redS[4][16][8];
    unsigned int* A32 = reinterpret_cast<unsigned int*>(A);

    int n0 = tile * 64, dq = t >> 4;
    const float* fb = features + (size_t)b * 1048576 + (size_t)dq * 16 * 4096 + n0 + l * 4;
    unsigned int u[4][8];
    float s[4] = {0, 0, 0, 0}, s2[4] = {0, 0, 0, 0};
#pragma unroll
    for (int p = 0; p < 16; ++p) {
        float4 v = *reinterpret_cast<const float4*>(fb + (size_t)p * 4096);
        s[0] += v.x; s2[0] += v.x * v.x;
        s[1] += v.y; s2[1] += v.y * v.y;
        s[2] += v.z; s2[2] += v.z * v.z;
        s[3] += v.w; s2[3] += v.w * v.w;
        unsigned int b0 = f2bf(v.x), b1_ = f2bf(v.y), b2_ = f2bf(v.z), b3_ = f2bf(v.w);
        if ((p & 1) == 0) {
            u[0][p >> 1] = b0; u[1][p >> 1] = b1_; u[2][p >> 1] = b2_; u[3][p >> 1] = b3_;
        } else {
            u[0][p >> 1] |= b0 << 16; u[1][p >> 1] |= b1_ << 16;
            u[2][p >> 1] |= b2_ << 16; u[3][p >> 1] |= b3_ << 16;
        }
    }
#pragma unroll
    for (int k = 0; k < 4; ++k) {
        s[k]  += __shfl_xor(s[k], 16, 64);  s[k]  += __shfl_xor(s[k], 32, 64);
        s2[k] += __shfl_xor(s2[k], 16, 64); s2[k] += __shfl_xor(s2[k], 32, 64);
    }
    if (lane < 16) {
        *reinterpret_cast<float4*>(&redS[wv][lane][0]) = make_float4(s[0], s[1], s[2], s[3]);
        *reinterpret_cast<float4*>(&redS[wv][lane][4]) = make_float4(s2[0], s2[1], s2[2], s2[3]);
    }
    __syncthreads();
    float mm[4], rr[4];
#pragma unroll
    for (int k = 0; k < 4; ++k) {
        float ts_ = redS[0][l][k] + redS[1][l][k] + redS[2][l][k] + redS[3][l][k];
        float t2  = redS[0][l][4 + k] + redS[1][l][4 + k] + redS[2][l][4 + k] + redS[3][l][4 + k];
        float mean = ts_ * (1.f / 256.f);
        float var = t2 * (1.f / 256.f) - mean * mean;
        mm[k] = mean; rr[k] = rsqrtf(var + 1e-5f);
    }
    float gg[16], ee[16];
#pragma unroll
    for (int j4 = 0; j4 < 4; ++j4) {
        *reinterpret_cast<float4*>(&gg[j4 * 4]) =
            *reinterpret_cast<const float4*>(fn_g + dq * 16 + j4 * 4);
        *reinterpret_cast<float4*>(&ee[j4 * 4]) =
            *reinterpret_cast<const float4*>(fn_b + dq * 16 + j4 * 4);
    }
#pragma unroll
    for (int k = 0; k < 4; ++k) {
        int rowl = l * 4 + k;
        unsigned int w[8];
#pragma unroll
        for (int j = 0; j < 8; ++j) {
            float x0 = bf2f(u[k][j]), x1 = bf2f(u[k][j] >> 16);
            unsigned int lo = f2bf((x0 - mm[k]) * rr[k] * gg[2 * j] + ee[2 * j]);
            unsigned int hi = f2bf((x1 - mm[k]) * rr[k] * gg[2 * j + 1] + ee[2 * j + 1]);
            w[j] = lo | (hi << 16);
        }
        uint4* dst = reinterpret_cast<uint4*>(&A32[rowl * 132 + dq * 8]);
        dst[0] = make_uint4(w[0], w[1], w[2], w[3]);
        dst[1] = make_uint4(w[4], w[5], w[6], w[7]);
    }
    __syncthreads();
    int ch = t & 31, rw = t >> 5;
    unsigned short* dst = ft + ((size_t)b * 4096 + n0) * 256;
#pragma unroll
    for (int ps = 0; ps < 8; ++ps) {
        int row = ps * 8 + rw;
        uint4 vv = *reinterpret_cast<const uint4*>(&A[row * 264 + ch * 8]);
        *reinterpret_cast<uint4*>(dst + (size_t)row * 256 + ch * 8) = vv;
    }
}

// ---------------- B: prologue finishes step k-1; scores + atomic Sigma e*f ----------
__global__ __launch_bounds__(256, 8) void k_score(
    const float* __restrict__ qpr, const float* __restrict__ qct,
    const unsigned short* __restrict__ ft, float* __restrict__ mask,
    float* __restrict__ escore, float* __restrict__ accs,
    float* __restrict__ sumev, float* __restrict__ out_amap, int kstep) {
    int c = blockIdx.x, b = blockIdx.y, t = threadIdx.x;
    int lane = t & 63, wv = t >> 6;
    __shared__ __align__(16) float qs[256];
    __shared__ float lmsk[64];
    __shared__ __align__(16) float part2[4][256];
    __shared__ float sred[16];
    if (kstep > 0) {
        if (t < 64) {
            int n = c * 64 + t;
            float inv = 1.f / accs[(kstep - 1) * 128 + b];
            float e = escore[(size_t)b * 4096 + n];
            float m = mask[(size_t)b * 4096 + n];
            float a = fmaxf(e * inv, 1e-8f);
            out_amap[((size_t)(b * 6 + kstep - 1)) * 4096 + n] = a;
            float nm = fmaxf(m * (1.f - 0.9f * a), 1e-6f);
            mask[(size_t)b * 4096 + n] = nm;
            lmsk[t] = logf(nm);
        }
    } else if (t < 64) lmsk[t] = 0.f;
    qs[t] = qpr[b * 256 + t];
    __syncthreads();
    int l = t & 15, rgp = t >> 4;       // 16 lanes per row, 16 row-groups
    float qq[16];
#pragma unroll
    for (int i = 0; i < 16; ++i) qq[i] = qs[l * 16 + i];
    float qc = qct[b];
    float acc[16];
#pragma unroll
    for (int i = 0; i < 16; ++i) acc[i] = 0.f;
    float dsum = 0.f, erow = 0.f, ecol = 0.f, elg = 0.f;
    const unsigned short* fb = ft + ((size_t)b * 4096 + c * 64) * 256 + l * 16;
#pragma unroll 2
    for (int rr = 0; rr < 4; ++rr) {
        int nl = rr * 16 + rgp;
        int n = c * 64 + nl;
        const uint4* p = reinterpret_cast<const uint4*>(fb + (size_t)nl * 256);
        uint4 r0 = p[0], r1 = p[1];
        float v[16];
        v[0]  = bf2f(r0.x); v[1]  = bf2f(r0.x >> 16);
        v[2]  = bf2f(r0.y); v[3]  = bf2f(r0.y >> 16);
        v[4]  = bf2f(r0.z); v[5]  = bf2f(r0.z >> 16);
        v[6]  = bf2f(r0.w); v[7]  = bf2f(r0.w >> 16);
        v[8]  = bf2f(r1.x); v[9]  = bf2f(r1.x >> 16);
        v[10] = bf2f(r1.y); v[11] = bf2f(r1.y >> 16);
        v[12] = bf2f(r1.z); v[13] = bf2f(r1.z >> 16);
        v[14] = bf2f(r1.w); v[15] = bf2f(r1.w >> 16);
        float dot = 0.f;
#pragma unroll
        for (int i = 0; i < 16; ++i) dot += v[i] * qq[i];
        dot += __shfl_xor(dot, 1, 64);
        dot += __shfl_xor(dot, 2, 64);
        dot += __shfl_xor(dot, 4, 64);
        dot += __shfl_xor(dot, 8, 64);
        float sc = (dot + qc) * 0.0625f + lmsk[nl];
        sc = fminf(fmaxf(sc, -50.f), 50.f);
        float lg = fminf(fmaxf(sc * 2.f, -50.f), 50.f);   // /TEMP, TEMP=0.5; lg = ln e
        float e = expf(lg);
        if (l == 0) escore[(size_t)b * 4096 + n] = e;
        dsum += e; elg += e * lg;
        erow += e * (float)(n >> 6);
        ecol += e * (float)(n & 63);
#pragma unroll
        for (int i = 0; i < 16; ++i) acc[i] += e * v[i];
    }
#pragma unroll
    for (int i = 0; i < 16; ++i) {
        acc[i] += __shfl_xor(acc[i], 16, 64);
        acc[i] += __shfl_xor(acc[i], 32, 64);
    }
    if (lane < 16) {
#pragma unroll
        for (int i4 = 0; i4 < 4; ++i4)
            *reinterpret_cast<float4*>(&part2[wv][lane * 16 + i4 * 4]) =
                make_float4(acc[i4 * 4], acc[i4 * 4 + 1], acc[i4 * 4 + 2], acc[i4 * 4 + 3]);
    }
    dsum *= 0.0625f; erow *= 0.0625f; ecol *= 0.0625f; elg *= 0.0625f;
#pragma unroll
    for (int off = 32; off > 0; off >>= 1) {
        dsum += __shfl_down(dsum, off, 64);
        erow += __shfl_down(erow, off, 64);
        ecol += __shfl_down(ecol, off, 64);
        elg  += __shfl_down(elg, off, 64);
    }
    if (lane == 0) {
        sred[wv] = dsum; sred[4 + wv] = erow; sred[8 + wv] = ecol; sred[12 + wv] = elg;
    }
    __syncthreads();
    if (t == 0) {
        atomicAdd(&accs[kstep * 128 + b],      sred[0] + sred[1] + sred[2] + sred[3]);
        atomicAdd(&accs[kstep * 128 + 32 + b], sred[4] + sred[5] + sred[6] + sred[7]);
        atomicAdd(&accs[kstep * 128 + 64 + b], sred[8] + sred[9] + sred[10] + sred[11]);
        atomicAdd(&accs[kstep * 128 + 96 + b], sred[12] + sred[13] + sred[14] + sred[15]);
    }
    float sum = part2[0][t] + part2[1][t] + part2[2][t] + part2[3][t];
    atomicAdd(&sumev[b * 256 + t], sum);
}

// ---------------- gemmA: blocks 0..3 stop partials; 4..27 gi = Wiv@abar + biv;
// 28..51 gh = whh@stateT + bhh. Weight-stationary, one read per weight. ----------
__global__ void k_gemmA(
    const float* __restrict__ Wiv, const float* __restrict__ biv,
    const float* __restrict__ whh, const float* __restrict__ bhh,
    const float* __restrict__ Wsv, const float* __restrict__ bsv,
    const float* __restrict__ wsv256, const float* __restrict__ sw2,
    const float* __restrict__ sumev, const float* __restrict__ stT_cur,
    const float* __restrict__ accs, float* __restrict__ giG,
    float* __restrict__ ghG, float* __restrict__ stopp, int kstep) {
    __shared__ float xL[8448];          // [256][33] padded
    __shared__ float wL[4096];          // 32 rows x 128 cols chunk
    __shared__ float pB[8][32];
    int blk = blockIdx.x, t = threadIdx.x;
    int rg = t >> 5, b = t & 31;
    int mode, r0;
    const float* W;
    if (blk < 4)       { mode = 0; r0 = blk * 32;        W = Wsv + (size_t)r0 * 256; }
    else if (blk < 28) { mode = 1; r0 = (blk - 4) * 32;  W = Wiv + (size_t)r0 * 256; }
    else               { mode = 2; r0 = (blk - 28) * 32; W = whh + (size_t)r0 * 256; }
    if (mode == 2) {
#pragma unroll
        for (int j = 0; j < 8; ++j) {
            int i4 = j * 256 + t;
            int fi = i4 * 4, d = fi >> 5, bb = fi & 31;
            float4 v = reinterpret_cast<const float4*>(stT_cur)[i4];
            xL[d * 33 + bb] = v.x;     xL[d * 33 + bb + 1] = v.y;
            xL[d * 33 + bb + 2] = v.z; xL[d * 33 + bb + 3] = v.w;
        }
    } else {
        int b_ = t >> 3, dc = t & 7;
        float invb = 1.f / accs[kstep * 128 + b_];
#pragma unroll
        for (int j4 = 0; j4 < 8; ++j4) {
            int d0 = j4 * 32 + dc * 4;
            float4 v = *reinterpret_cast<const float4*>(sumev + b_ * 256 + d0);
            xL[(d0 + 0) * 33 + b_] = v.x * invb;
            xL[(d0 + 1) * 33 + b_] = v.y * invb;
            xL[(d0 + 2) * 33 + b_] = v.z * invb;
            xL[(d0 + 3) * 33 + b_] = v.w * invb;
        }
    }
    float acc[4] = {0, 0, 0, 0};
    for (int ch = 0; ch < 2; ++ch) {
        __syncthreads();
#pragma unroll
        for (int jj = 0; jj < 4; ++jj) {
            int i4 = jj * 256 + t;
            int row = i4 >> 5, c4 = i4 & 31;
            reinterpret_cast<float4*>(wL)[i4] =
                *reinterpret_cast<const float4*>(W + (size_t)row * 256 + ch * 128 + c4 * 4);
        }
        __syncthreads();
#pragma unroll 8
        for (int d = 0; d < 128; ++d) {
            float xv = xL[(ch * 128 + d) * 33 + b];
            acc[0] += wL[(rg * 4 + 0) * 128 + d] * xv;
            acc[1] += wL[(rg * 4 + 1) * 128 + d] * xv;
            acc[2] += wL[(rg * 4 + 2) * 128 + d] * xv;
            acc[3] += wL[(rg * 4 + 3) * 128 + d] * xv;
        }
    }
    if (mode == 0) {
        float S = accs[kstep * 128 + b];
        float ent = -(accs[kstep * 128 + 96 + b] / S - logf(S)) * 0.12022458674074826f;
        float gsum = 0.f;
#pragma unroll
        for (int k2 = 0; k2 < 4; ++k2) {
            int sr = r0 + rg * 4 + k2;
            float av = acc[k2] + bsv[sr] + ent * wsv256[sr];
            gsum += gelu_exact(av) * sw2[sr];
        }
        pB[rg][b] = gsum;
        __syncthreads();
        if (t < 32)
            stopp[blk * 32 + t] = pB[0][t] + pB[1][t] + pB[2][t] + pB[3][t]
                                + pB[4][t] + pB[5][t] + pB[6][t] + pB[7][t];
    } else {
        float* out = (mode == 1) ? giG : ghG;
        const float* bias = (mode == 1) ? biv + r0 : bhh + r0;
#pragma unroll
        for (int k2 = 0; k2 < 4; ++k2)
            out[(size_t)(r0 + rg * 4 + k2) * 32 + b] = acc[k2] + bias[rg * 4 + k2];
    }
}

// ---------------- finq: h-combine -> LN -> qln (LDS) -> qpr rows via M-GEMM.
// Block 0: stateT(next), stop/cent outputs, qct. k==5: outputs + amap(5). ----------
__global__ void k_finq(
    const float* __restrict__ giG, const float* __restrict__ ghG,
    const float* __restrict__ stT_cur, float* __restrict__ stT_nxt,
    const float* __restrict__ clueT, const float* __restrict__ qn_g,
    const float* __restrict__ qn_b, const float* __restrict__ M,
    const float* __restrict__ m0, const float* __restrict__ u,
    const float* __restrict__ c0v, const float* __restrict__ accs,
    const float* __restrict__ stopp, const float* __restrict__ sb2,
    const float* __restrict__ escore, float* __restrict__ out_amap,
    float* __restrict__ sumev_nxt, float* __restrict__ qpr,
    float* __restrict__ qct, float* __restrict__ out_cent,
    float* __restrict__ out_stop, int kstep) {
    int blk = blockIdx.x, t = threadIdx.x;
    if (kstep == 5) {
        if (blk == 0) {
            if (t < 32) {
                int bb = t;
                float inv = 1.f / accs[5 * 128 + bb];
                float sraw = sb2[0] + stopp[bb] + stopp[32 + bb] + stopp[64 + bb] + stopp[96 + bb];
                out_stop[bb * 6 + 5] = 4.f * tanhf(sraw * 0.25f);
                out_cent[(bb * 6 + 5) * 2 + 0] = accs[5 * 128 + 32 + bb] * inv;
                out_cent[(bb * 6 + 5) * 2 + 1] = accs[5 * 128 + 64 + bb] * inv;
            }
        } else {
            int b = blk - 1;
            float inv = 1.f / accs[5 * 128 + b];
#pragma unroll
            for (int j = 0; j < 4; ++j) {
                int n4 = (j * 256 + t) * 4;
                float4 e4 = *reinterpret_cast<const float4*>(&escore[(size_t)b * 4096 + n4]);
                *reinterpret_cast<float4*>(&out_amap[((size_t)(b * 6 + 5)) * 4096 + n4]) =
                    make_float4(fmaxf(e4.x * inv, 1e-8f), fmaxf(e4.y * inv, 1e-8f),
                                fmaxf(e4.z * inv, 1e-8f), fmaxf(e4.w * inv, 1e-8f));
            }
        }
        return;
    }
    __shared__ float qsh[8192];       // [256][32]
    __shared__ float wL[4096];        // 16 rows x 256
    __shared__ float redp1[8][32], redp2[8][32];
    __shared__ float muS[32], rsS[32];
    int b = t & 31, dg = t >> 5;
    if (t < 128)
        *reinterpret_cast<float4*>(sumev_nxt + blk * 512 + t * 4) = make_float4(0, 0, 0, 0);
    float s = 0.f, s2 = 0.f;
#pragma unroll
    for (int j = 0; j < 32; ++j) {
        int d = dg * 32 + j;
        float gir = giG[(size_t)d * 32 + b],         ghr = ghG[(size_t)d * 32 + b];
        float giz = giG[(size_t)(256 + d) * 32 + b], ghz = ghG[(size_t)(256 + d) * 32 + b];
        float gin = giG[(size_t)(512 + d) * 32 + b], ghn = ghG[(size_t)(512 + d) * 32 + b];
        float hp = stT_cur[d * 32 + b];
        float r = 1.f / (1.f + expf(-(gir + ghr)));
        float z = 1.f / (1.f + expf(-(giz + ghz)));
        float nn = tanhf(gin + r * ghn);
        float h = (1.f - z) * nn + z * hp;
        if (blk == 0) stT_nxt[d * 32 + b] = h;
        float x = clueT[(size_t)(kstep + 1) * 8192 + d * 32 + b] + h;
        qsh[d * 32 + b] = x;
        s += x; s2 += x * x;
    }
    redp1[dg][b] = s; redp2[dg][b] = s2;
    __syncthreads();
    if (t < 32) {
        float ss = 0.f, qq = 0.f;
#pragma unroll
        for (int g = 0; g < 8; ++g) { ss += redp1[g][t]; qq += redp2[g][t]; }
        float mu = ss * (1.f / 256.f);
        float var = qq * (1.f / 256.f) - mu * mu;
        muS[t] = mu; rsS[t] = rsqrtf(var + 1e-5f);
    }
    __syncthreads();
    float mu = muS[b], rs = rsS[b];
#pragma unroll
    for (int j = 0; j < 32; ++j) {
        int d = dg * 32 + j;
        float x = qsh[d * 32 + b];
        qsh[d * 32 + b] = (x - mu) * rs * qn_g[d] + qn_b[d];
    }
    __syncthreads();
    if (blk == 0) {
        float pc = 0.f;
#pragma unroll
        for (int j = 0; j < 32; ++j) {
            int d = dg * 32 + j;
            pc += u[d] * qsh[d * 32 + b];
        }
        redp1[dg][b] = pc;
        if (t < 32) {
            int bb = t;
            float inv = 1.f / accs[kstep * 128 + bb];
            float sraw = sb2[0] + stopp[bb] + stopp[32 + bb] + stopp[64 + bb] + stopp[96 + bb];
            out_stop[bb * 6 + kstep] = 4.f * tanhf(sraw * 0.25f);
            out_cent[(bb * 6 + kstep) * 2 + 0] = accs[kstep * 128 + 32 + bb] * inv;
            out_cent[(bb * 6 + kstep) * 2 + 1] = accs[kstep * 128 + 64 + bb] * inv;
        }
        __syncthreads();
        if (t < 32) {
            float q = c0v[0];
#pragma unroll
            for (int g = 0; g < 8; ++g) q += redp1[g][t];
            qct[t] = q;
        }
    }
    int r0 = blk * 16;
#pragma unroll
    for (int jj = 0; jj < 4; ++jj) {
        int i4 = jj * 256 + t;
        int row = i4 >> 6, c4 = i4 & 63;
        reinterpret_cast<float4*>(wL)[i4] =
            *reinterpret_cast<const float4*>(M + (size_t)(r0 + row) * 256 + c4 * 4);
    }
    __syncthreads();
    int rg = t >> 5;
    float a0 = 0.f, a1 = 0.f;
#pragma unroll 8
    for (int d = 0; d < 256; ++d) {
        float xv = qsh[d * 32 + b];
        a0 += wL[(rg * 2 + 0) * 256 + d] * xv;
        a1 += wL[(rg * 2 + 1) * 256 + d] * xv;
    }
    qpr[(size_t)b * 256 + r0 + rg * 2 + 0] = a0 + m0[r0 + rg * 2 + 0];
    qpr[(size_t)b * 256 + r0 + rg * 2 + 1] = a1 + m0[r0 + rg * 2 + 1];
}

// ---------------- GEMM3 (preloop only): qpr = M@qln0 + m0 ; qct = u.qln0 + c0 ----------
__global__ __launch_bounds__(256, 2) void k_gemm3(
    const float* __restrict__ M, const float* __restrict__ m0,
    const float* __restrict__ u, const float* __restrict__ c0v,
    const float* __restrict__ qlnG, float* __restrict__ qpr,
    float* __restrict__ qct) {
    __shared__ float xL[8192];
    __shared__ float wL[8192];
    __shared__ float pB[8][32];
    int blk = blockIdx.x, t = threadIdx.x;
    int r0 = blk * 32;
    float4* xL4 = reinterpret_cast<float4*>(xL);
    float4* wL4 = reinterpret_cast<float4*>(wL);
    const float4* Xg4 = reinterpret_cast<const float4*>(qlnG);
    const float4* Wg4 = reinterpret_cast<const float4*>(M + (size_t)r0 * 256);
#pragma unroll
    for (int j = 0; j < 8; ++j) {
        xL4[j * 256 + t] = Xg4[j * 256 + t];
        wL4[j * 256 + t] = Wg4[j * 256 + t];
    }
    __syncthreads();
    int rg = t >> 5, b = t & 31;
    float acc[4] = {0, 0, 0, 0};
#pragma unroll 8
    for (int d = 0; d < 256; ++d) {
        float xv = xL[d * 32 + b];
        acc[0] += wL[(rg * 4 + 0) * 256 + d] * xv;
        acc[1] += wL[(rg * 4 + 1) * 256 + d] * xv;
        acc[2] += wL[(rg * 4 + 2) * 256 + d] * xv;
        acc[3] += wL[(rg * 4 + 3) * 256 + d] * xv;
    }
#pragma unroll
    for (int k2 = 0; k2 < 4; ++k2) {
        int row = r0 + rg * 4 + k2;
        qpr[(size_t)b * 256 + row] = acc[k2] + m0[row];
    }
    if (blk == 0) {
        float sv = 0.f;
#pragma unroll 8
        for (int dd = 0; dd < 32; ++dd) {
            int d = rg * 32 + dd;
            sv += u[d] * xL[d * 32 + b];
        }
        pB[rg][b] = sv;
        __syncthreads();
        if (t < 32)
            qct[t] = pB[0][t] + pB[1][t] + pB[2][t] + pB[3][t]
                   + pB[4][t] + pB[5][t] + pB[6][t] + pB[7][t] + c0v[0];
    }
}

extern "C" void kernel_launch(void* const* d_in, const int* in_sizes, int n_in,
                              void* d_out, int out_size, void* d_ws, size_t ws_size,
                              hipStream_t stream) {
    const float* features     = (const float*)d_in[0];
    const float* task_context = (const float*)d_in[1];
    const float* ctx_w1 = (const float*)d_in[2];
    const float* ctx_b1 = (const float*)d_in[3];
    const float* ctx_w2 = (const float*)d_in[4];
    const float* ctx_b2 = (const float*)d_in[5];
    const float* q_w = (const float*)d_in[6];
    const float* q_b = (const float*)d_in[7];
    const float* k_w = (const float*)d_in[8];
    const float* k_b = (const float*)d_in[9];
    const float* v_w = (const float*)d_in[10];
    const float* v_b = (const float*)d_in[11];
    const float* qn_g = (const float*)d_in[12];
    const float* qn_b = (const float*)d_in[13];
    const float* fn_g = (const float*)d_in[14];
    const float* fn_b = (const float*)d_in[15];
    const float* stop_w1 = (const float*)d_in[16];
    const float* stop_b1 = (const float*)d_in[17];
    const float* stop_w2 = (const float*)d_in[18];
    const float* stop_b2 = (const float*)d_in[19];
    const float* gru_wih = (const float*)d_in[20];
    const float* gru_bih = (const float*)d_in[21];
    const float* gru_whh = (const float*)d_in[22];
    const float* gru_bhh = (const float*)d_in[23];

    // workspace layout (~67 MB)
    unsigned short* ft = (unsigned short*)d_ws;             // [32][4096][256] bf16
    float* fbase  = (float*)(ft + (size_t)NB * NN_ * ND);
    float* clueT  = fbase;                    // [6][256][32]
    float* stateT0= clueT + 6 * ND * NB;      // [256][32]
    float* stateT1= stateT0 + ND * NB;        // [256][32]
    float* qpr    = stateT1 + ND * NB;        // [32][256]
    float* qlnG   = qpr + NB * ND;            // [256][32]
    float* mask   = qlnG + ND * NB;           // [32][4096]
    float* escore = mask + NB * NN_;          // [32][4096]
    float* accz   = escore + NB * NN_;        // accs768 | stopp128 | pad128
    float* accs   = accz;
    float* stopp  = accz + 768;
    float* sumev0 = accz + 1024;              // [32][256]
    float* sumev1 = sumev0 + NB * ND;         // [32][256]
    float* M      = sumev1 + NB * ND;         // [256][256]
    float* m0     = M + 65536;                // [256]
    float* u      = m0 + 256;                 // [256]
    float* c0v    = u + 256;                  // [16]
    float* Wiv    = c0v + 16;                 // [768][256]
    float* biv    = Wiv + 768 * 256;          // [768]
    float* Wsv    = biv + 768;                // [128][256]
    float* bsv    = Wsv + 128 * 256;          // [128]
    float* wsv256 = bsv + 128;                // [128]
    float* qctG   = wsv256 + 128;             // [32]

    float* out_cent = (float*)d_out;          // (B,K,2)
    float* out_amap = out_cent + NB * NK * 2; // (B,K,H,W)
    float* out_stop = out_amap + (size_t)NB * NK * NN_; // (B,K)

    float* sumev[2] = {sumev0, sumev1};
    float* stT[2] = {stateT0, stateT1};

    k_setup<<<609, 256, 0, stream>>>(mask, accz, sumev0, stateT0,
                                     M, m0, u, c0v, Wiv, biv, Wsv, bsv, wsv256,
                                     clueT, qlnG,
                                     k_w, q_w, q_b, k_b, gru_wih, gru_bih, v_b,
                                     stop_w1, stop_b1, task_context,
                                     ctx_w1, ctx_b1, ctx_w2, ctx_b2, qn_g, qn_b);
    k_setupW<<<229, 256, 0, stream>>>(gru_wih, gru_bih, v_w, v_b, stop_w1, stop_b1,
                                      k_w, q_w, q_b, k_b,
                                      Wiv, biv, Wsv, bsv, wsv256, m0, u, c0v);
    k_ln<<<dim3(64, 32), 256, 0, stream>>>(features, fn_g, fn_b, ft);
    k_gemm3<<<8, 256, 0, stream>>>(M, m0, u, c0v, qlnG, qpr, qctG);
    for (int k = 0; k < NK; ++k) {
        k_score<<<dim3(64, 32), 256, 0, stream>>>(qpr, qctG, ft, mask, escore, accs,
                                                  sumev[k & 1], out_amap, k);
        k_gemmA<<<(k == 5 ? 4 : 52), 256, 0, stream>>>(Wiv, biv, gru_whh, gru_bhh,
                                                       Wsv, bsv, wsv256, stop_w2,
                                                       sumev[k & 1], stT[k & 1], accs,
                                                       (float*)(Wiv + 0) == nullptr ? nullptr : /*giG*/ (float*)(qctG + 32),
                                                       (float*)(qctG + 32 + 768 * 32),
                                                       stopp, k);
        k_finq<<<(k == 5 ? 33 : 16), 256, 0, stream>>>(
            (const float*)(qctG + 32), (const float*)(qctG + 32 + 768 * 32),
            stT[k & 1], stT[(k + 1) & 1], clueT, qn_g, qn_b, M, m0, u, c0v,
            accs, stopp, stop_b2, escore, out_amap, sumev[(k + 1) & 1],
            qpr, qctG, out_cent, out_stop, k);
    }
}